// Round 16
// baseline (49.991 us; speedup 1.0000x reference)
//
#include <hip/hip_runtime.h>
#include <hip/hip_fp16.h>
#include <math.h>

#define NPIXD 1024
#define GD    2048
#define NCHAND 4
#define NVISD 200000
#define KXROWS 408     // kx rows computed/stored (gather needs <=403; clamped)
#define YPACK  832     // centered packing: pos = y_signed + 416
#define FINP   1024    // Fin row pitch (half2 slots)
#define IDX(i) ((i) + ((i) >> 4))   // LDS pad
#define RSQ2   0.70710678118654752f

#define FH_SCALE   1048576.0f       // 2^20 net scale of FhH
#define FH_ISCALE  (1.0f / 1048576.0f)
#define FIN_SCALE  4194304.0f       // 2^22 scale carried through FFT stages (fp16 LDS)
#define FIN_TO_FH  0.25f            // 2^22 -> 2^20
#define FIN_TO_IM  (1.0f / 4194304.0f)

static constexpr double PI_D = 3.14159265358979323846;
static constexpr float SCALE_F = (float)(1000.0 * 0.005 * PI_D / (180.0 * 3600.0) * 2048.0);
static constexpr float BETA_F  = (float)(2.34 * 6.0);

// inline apodization: for i in [0,1024), arg >= 173 > 0 always
__device__ __forceinline__ float apodf(int i) {
    float n  = (float)(i - 512) * (1.0f / 2048.0f);
    float t  = (float)(PI_D * 6.0) * n;
    float arg = BETA_F * BETA_F - t * t;
    float sq = sqrtf(arg);
    float e  = __expf(sq);
    return sq * 2.0f / (e - 1.0f / e);     // sq / sinh(sq)
}

__device__ __forceinline__ float2 cadd(float2 a, float2 b){ return make_float2(a.x+b.x, a.y+b.y); }
__device__ __forceinline__ float2 csub(float2 a, float2 b){ return make_float2(a.x-b.x, a.y-b.y); }
__device__ __forceinline__ float2 cmulf(float2 a, float2 b){ return make_float2(a.x*b.x - a.y*b.y, a.x*b.y + a.y*b.x); }
__device__ __forceinline__ float2 cnegi(float2 a){ return make_float2(a.y, -a.x); }

__device__ __forceinline__ float2 h2f(__half2 h){ return __half22float2(h); }
__device__ __forceinline__ __half2 f2h(float2 f){ return __floats2half2_rn(f.x, f.y); }

// twiddle exp(-i*pi*e/1024); e integer-valued <= 1785 (fp32-exact)
__device__ __forceinline__ float2 twf(float e) {
    float s, c;
    __sincosf(e * (float)(-PI_D / 1024.0), &s, &c);
    return make_float2(c, s);
}

// DFT8 with x2..x5 == 0
__device__ __forceinline__ void dft8_sparse(float2 x0, float2 x1, float2 x6, float2 x7,
                                            float2 y[8]) {
    float2 u0 = cadd(x0,x6), u1 = csub(x0,x6), u2 = cadd(x1,x7), u3 = cnegi(csub(x1,x7));
    y[0]=cadd(u0,u2); y[2]=cadd(u1,u3); y[4]=csub(u0,u2); y[6]=csub(u1,u3);
    float2 o0 = x0;
    float2 o1 = make_float2(RSQ2*(x1.x + x1.y), RSQ2*(x1.y - x1.x));
    float2 o2 = make_float2(-x6.y, x6.x);
    float2 o3 = make_float2(RSQ2*(x7.x - x7.y), RSQ2*(x7.y + x7.x));
    float2 v0 = cadd(o0,o2), v1 = csub(o0,o2), v2 = cadd(o1,o3), v3 = cnegi(csub(o1,o3));
    y[1]=cadd(v0,v2); y[3]=cadd(v1,v3); y[5]=csub(v0,v2); y[7]=csub(v1,v3);
}

__device__ __forceinline__ void dft8_full(const float2 x[8], float2 y[8]) {
    float2 e0=cadd(x[0],x[4]), e1=cadd(x[1],x[5]), e2=cadd(x[2],x[6]), e3=cadd(x[3],x[7]);
    float2 o0=csub(x[0],x[4]), o1=csub(x[1],x[5]), o2=csub(x[2],x[6]), o3=csub(x[3],x[7]);
    o1 = make_float2(RSQ2*(o1.x + o1.y), RSQ2*(o1.y - o1.x));
    o2 = cnegi(o2);
    o3 = make_float2(RSQ2*(o3.y - o3.x), -RSQ2*(o3.x + o3.y));
    float2 u0=cadd(e0,e2), u1=csub(e0,e2), u2=cadd(e1,e3), u3=cnegi(csub(e1,e3));
    y[0]=cadd(u0,u2); y[2]=cadd(u1,u3); y[4]=csub(u0,u2); y[6]=csub(u1,u3);
    float2 v0=cadd(o0,o2), v1=csub(o0,o2), v2=cadd(o1,o3), v3=cnegi(csub(o1,o3));
    y[1]=cadd(v0,v2); y[3]=cadd(v1,v3); y[5]=csub(v0,v2); y[7]=csub(v1,v3);
}

// stage 0 (m=1, pm=j): sparse DFT8 from registers -> half2 buf
__device__ __forceinline__ void stage0_ip(float2 x0, float2 x1, float2 x6, float2 x7,
                                          __half2* __restrict__ buf) {
    int j = (int)threadIdx.x;
    float2 y[8];
    dft8_sparse(x0, x1, x6, x7, y);
    buf[IDX(8 * j)] = f2h(y[0]);
    #pragma unroll
    for (int t = 1; t < 8; ++t)
        buf[IDX(8 * j + t)] = f2h(cmulf(twf((float)(t * j)), y[t]));
}

// in-place radix-8 Stockham stage (fp16 LDS, fp32 math). m in {8, 64}
__device__ __forceinline__ void r8_ip(__half2* __restrict__ buf, int m) {
    int j = (int)threadIdx.x;
    float2 x[8];
    #pragma unroll
    for (int k = 0; k < 8; ++k) x[k] = h2f(buf[IDX(j + 256 * k)]);
    __syncthreads();
    float2 y[8];
    dft8_full(x, y);
    int pm = j & ~(m - 1);
    int base = 7 * pm + j;
    buf[IDX(base)] = f2h(y[0]);
    #pragma unroll
    for (int t = 1; t < 8; ++t)
        buf[IDX(base + t * m)] = f2h(cmulf(twf((float)(t * pm)), y[t]));
}

// final radix-4 (m=512, twiddle-free), PRUNED: only t=0 (j) and t=3 (j+1536) written
__device__ __forceinline__ void r4_final_ip(__half2* __restrict__ buf) {
    int j = (int)threadIdx.x;
    float2 v[8];
    #pragma unroll
    for (int h = 0; h < 2; ++h) {
        int jj = j + h * 256;
        v[h*4+0] = h2f(buf[IDX(jj)]);
        v[h*4+1] = h2f(buf[IDX(jj + 512)]);
        v[h*4+2] = h2f(buf[IDX(jj + 1024)]);
        v[h*4+3] = h2f(buf[IDX(jj + 1536)]);
    }
    __syncthreads();
    #pragma unroll
    for (int h = 0; h < 2; ++h) {
        int jj = j + h * 256;
        float2 a = v[h*4], b = v[h*4+1], cc = v[h*4+2], d = v[h*4+3];
        float2 u0 = cadd(a,cc), u1 = csub(a,cc), u2 = cadd(b,d), u3 = cnegi(csub(b,d));
        buf[IDX(jj)]        = f2h(cadd(u0,u2));   // t=0
        buf[IDX(jj + 1536)] = f2h(csub(u1,u3));   // t=3
    }
}

// ---------------- Kaiser-Bessel weights (used only for table fill) ----------------
__device__ __forceinline__ float i0f(float x) {
    float ax = fabsf(x);
    if (ax <= 3.75f) {
        float ts = ax / 3.75f; ts *= ts;
        return 1.0f + ts * (3.5156229f + ts * (3.0899424f + ts * (1.2067492f +
                     ts * (0.2659732f + ts * (0.0360768f + ts * 0.0045813f)))));
    } else {
        float t = 3.75f / ax;
        return expf(ax) / sqrtf(ax) *
               (0.39894228f + t * (0.01328592f + t * (0.00225319f + t * (-0.00157565f +
                t * (0.00916281f + t * (-0.02057706f + t * (0.02635537f +
                t * (-0.01647633f + t * 0.00392377f))))))));
    }
}

__device__ __forceinline__ float kbwf(float dist) {
    float r = dist * (2.0f / 6.0f);
    float s = 1.0f - r * r;
    if (s <= 0.0f) return 0.0f;
    return i0f(BETA_F * sqrtf(s)) * (1.0f / 6.0f);
}

// ---------------- pass 1 FUSED: 2 CONSECUTIVE row-pairs/block (y0..y0+3), half2 Fin ----
// Inputs pre-scaled by FIN_SCALE (folded into ay) so fp16 stages stay in normal range;
// epilogue therefore stores WITHOUT further scaling.
__global__ __launch_bounds__(256) void fft_rows_fused(const float* __restrict__ img,
                                                      unsigned int* __restrict__ FinU) {
    __shared__ __half2 buf[2176];
    __shared__ unsigned int stg[KXROWS * 5];   // 4 half2 per kx + pad (pitch 5)
    int j  = (int)threadIdx.x;
    int bx = (int)blockIdx.x;                  // 0..255
    int c  = (int)blockIdx.y;
    int w  = (bx & 7) * 32 + (bx >> 3);        // bijective on [0,256); same-XCD w consecutive
    int y0 = w * 4;
    float a0 = apodf(j + 512), a1 = apodf(j + 768), a6 = apodf(j), a7 = apodf(j + 256);
    float ay[4];
    #pragma unroll
    for (int p = 0; p < 4; ++p) ay[p] = apodf(y0 + p) * FIN_SCALE;  // 2^22 pre-scale
    float rA[4][4];
    #pragma unroll
    for (int p = 0; p < 4; ++p) {
        const float* rp = img + ((size_t)c * NPIXD + y0 + p) * NPIXD;
        rA[p][0] = rp[j + 512]; rA[p][1] = rp[j + 768];
        rA[p][2] = rp[j];       rA[p][3] = rp[j + 256];
    }
    #pragma unroll
    for (int q = 0; q < 2; ++q) {
        int pa = 2 * q, pb = 2 * q + 1;
        float ay1 = ay[pa], ay2 = ay[pb];
        float2 x0 = make_float2(rA[pa][0] * a0 * ay1, rA[pb][0] * a0 * ay2);
        float2 x1 = make_float2(rA[pa][1] * a1 * ay1, rA[pb][1] * a1 * ay2);
        float2 x6 = make_float2(rA[pa][2] * a6 * ay1, rA[pb][2] * a6 * ay2);
        float2 x7 = make_float2(rA[pa][3] * a7 * ay1, rA[pb][3] * a7 * ay2);
        __syncthreads();                     // buf free (prev epilogue reads done)
        stage0_ip(x0, x1, x6, x7, buf);
        __syncthreads();
        r8_ip(buf, 8);
        __syncthreads();
        r8_ip(buf, 64);
        __syncthreads();
        r4_final_ip(buf);
        __syncthreads();
        // Hermitian unpair epilogue -> stage (already 2^22-scaled)
        #pragma unroll
        for (int t = 0; t < 2; ++t) {
            int kx = j + t * 256;
            if (kx < KXROWS) {
                float2 Z  = h2f(buf[IDX(kx)]);
                float2 Zm = h2f(buf[IDX((GD - kx) & (GD - 1))]);
                __half2 h1 = f2h(make_float2(0.5f*(Z.x+Zm.x), 0.5f*(Z.y-Zm.y)));
                __half2 h2v = f2h(make_float2(0.5f*(Z.y+Zm.y), 0.5f*(Zm.x-Z.x)));
                stg[kx * 5 + pa] = *reinterpret_cast<unsigned int*>(&h1);
                stg[kx * 5 + pb] = *reinterpret_cast<unsigned int*>(&h2v);
            }
        }
    }
    __syncthreads();
    // write-out: one 16B chunk (4 half2 = rows y0..y0+3) per kx
    #pragma unroll
    for (int k = 0; k < 2; ++k) {
        int kx = j + 256 * k;
        if (kx < KXROWS) {
            unsigned int* dst = FinU + ((size_t)c * KXROWS + kx) * FINP + y0;
            const unsigned int* s = &stg[kx * 5];
            *reinterpret_cast<uint4*>(dst) = make_uint4(s[0], s[1], s[2], s[3]);
        }
    }
}

// ---------------- pass 2: col FFTs (fp16 LDS); Re -> half4 interleaved -----------------
// Block (0,0) additionally fills the 1025x8 KB-weight lerp table for the gather.
__global__ __launch_bounds__(256) void fft_cols(const unsigned int* __restrict__ FinU,
                                                __half* __restrict__ FhH,
                                                float* __restrict__ FhIm,
                                                float* __restrict__ Wtab,
                                                int writeIm) {
    __shared__ __half2 buf[2176];
    int j = (int)threadIdx.x;
    int kx = blockIdx.x, c = blockIdx.y;
    if (kx == 0 && c == 0) {
        for (int i = j; i <= 1024; i += 256) {
            float frac = (float)i * (1.0f / 1024.0f);
            float* rowp = Wtab + (size_t)i * 8;
            #pragma unroll
            for (int o = 0; o < 6; ++o) rowp[o] = kbwf(frac - (float)(o - 2));
            rowp[6] = 0.0f; rowp[7] = 0.0f;
        }
    }
    const unsigned int* inr = FinU + ((size_t)c * KXROWS + kx) * FINP;
    unsigned int u0 = inr[j + 512], u1 = inr[j + 768], u6 = inr[j], u7 = inr[j + 256];
    float2 x0 = h2f(*reinterpret_cast<__half2*>(&u0));
    float2 x1 = h2f(*reinterpret_cast<__half2*>(&u1));
    float2 x6 = h2f(*reinterpret_cast<__half2*>(&u6));
    float2 x7 = h2f(*reinterpret_cast<__half2*>(&u7));
    stage0_ip(x0, x1, x6, x7, buf);
    __syncthreads();
    r8_ip(buf, 8);
    __syncthreads();
    r8_ip(buf, 64);
    __syncthreads();
    r4_final_ip(buf);
    __syncthreads();
    // centered packing: n<416 -> pos n+416 (y=n); n>=1632 -> pos n-1632 (y=n-2048)
    __half* basep = FhH + ((size_t)kx * YPACK) * NCHAND + c;
    float*  imb   = FhIm + ((size_t)c * KXROWS + kx) * YPACK;
    for (int n = j; n < GD; n += 256) {
        int pos = -1;
        if (n < 416)         pos = n + 416;
        else if (n >= 1632)  pos = n - 1632;
        if (pos >= 0) {
            float2 z = h2f(buf[IDX(n)]);
            basep[(size_t)pos * NCHAND] = __float2half_rn(z.x * FIN_TO_FH);
            if (writeIm) imb[pos] = z.y * FIN_TO_IM;
        }
    }
}

// ---- 6-weight lookup with linear interpolation: w6[o] = w(frac - (o-2)) ----
__device__ __forceinline__ void wtab_lookup(const float* __restrict__ Wtab, float frac,
                                            float w6[6]) {
    float fu = frac * 1024.0f;
    int   iu = (int)fu;                 // 0..1023
    float aa = fu - (float)iu;
    const float4* rw = (const float4*)(Wtab + (size_t)iu * 8);
    float4 A0 = rw[0], A1 = rw[1], B0 = rw[2], B1 = rw[3];
    w6[0] = fmaf(aa, B0.x - A0.x, A0.x);
    w6[1] = fmaf(aa, B0.y - A0.y, A0.y);
    w6[2] = fmaf(aa, B0.z - A0.z, A0.z);
    w6[3] = fmaf(aa, B0.w - A0.w, A0.w);
    w6[4] = fmaf(aa, B1.x - A1.x, A1.x);
    w6[5] = fmaf(aa, B1.y - A1.y, A1.y);
}

// ---------------- gather_real (r15): dead complex path stripped; loads first ----------
__global__ __launch_bounds__(256) void gather_real(const float* __restrict__ uu,
                                                   const float* __restrict__ vv,
                                                   const float4* __restrict__ FhH4,
                                                   const float* __restrict__ Wtab,
                                                   float* __restrict__ out,
                                                   int out_elems) {
    int tid = (int)threadIdx.x;
    int v = tid >> 1, r = tid & 1;
    int gv = blockIdx.x * 128 + v;
    if (gv >= NVISD) return;
    float tx = uu[gv] * SCALE_F;
    float ty = vv[gv] * SCALE_F;
    float fxf = floorf(tx), fyf = floorf(ty);
    int fxi = (int)fxf, fyi = (int)fyf;

    int p0n = fyi + 414, p0c = 413 - fyi;
    p0n = min(max(p0n, 0), YPACK - 6);
    p0c = min(max(p0c, 0), YPACK - 6);
    int dn = p0n & 1, dc = p0c & 1;
    int f0n = (p0n - dn) >> 1, f0c = (p0c - dc) >> 1;

    const float4* rps[3];
    int cjs[3];
    #pragma unroll
    for (int bb = 0; bb < 3; ++bb) {
        int o = r * 3 + bb - 2;
        int ix = (fxi + o) & (GD - 1);
        int cj = (ix > 1024) ? 1 : 0;
        int kx = cj ? (GD - ix) : ix;
        kx = min(kx, KXROWS - 1);
        rps[bb] = FhH4 + (size_t)kx * (YPACK / 2) + (cj ? f0c : f0n);
        cjs[bb] = cj;
    }

    float4 Q[3][4];
    #pragma unroll
    for (int bb = 0; bb < 3; ++bb) {
        #pragma unroll
        for (int q = 0; q < 4; ++q) Q[bb][q] = rps[bb][q];
    }

    float wxf[6], wy[6];
    wtab_lookup(Wtab, tx - fxf, wxf);
    wtab_lookup(Wtab, ty - fyf, wy);
    float wn8[8], wc8[8];
    #pragma unroll
    for (int w = 0; w < 8; ++w) {
        int tn = w - dn; wn8[w] = (tn >= 0 && tn < 6) ? wy[tn] : 0.0f;
        int tc = w - dc; wc8[w] = (tc >= 0 && tc < 6) ? wy[5 - tc] : 0.0f;
    }

    float s0 = 0.0f, s1 = 0.0f, s2 = 0.0f, s3 = 0.0f;
    #pragma unroll
    for (int bb = 0; bb < 3; ++bb) {
        float wxb = wxf[r * 3 + bb];
        bool cj = cjs[bb] != 0;
        #pragma unroll
        for (int q = 0; q < 4; ++q) {
            float4 Qv = Q[bb][q];
            float w0 = wxb * (cj ? wc8[2 * q]     : wn8[2 * q]);
            float w1 = wxb * (cj ? wc8[2 * q + 1] : wn8[2 * q + 1]);
            float2 fa = __half22float2(*reinterpret_cast<const __half2*>(&Qv.x));
            float2 fb = __half22float2(*reinterpret_cast<const __half2*>(&Qv.y));
            float2 fc = __half22float2(*reinterpret_cast<const __half2*>(&Qv.z));
            float2 fd = __half22float2(*reinterpret_cast<const __half2*>(&Qv.w));
            s0 = fmaf(w0, fa.x, fmaf(w1, fc.x, s0));
            s1 = fmaf(w0, fa.y, fmaf(w1, fc.y, s1));
            s2 = fmaf(w0, fb.x, fmaf(w1, fd.x, s2));
            s3 = fmaf(w0, fb.y, fmaf(w1, fd.y, s3));
        }
    }
    s0 += __shfl_xor(s0, 1);
    s1 += __shfl_xor(s1, 1);
    s2 += __shfl_xor(s2, 1);
    s3 += __shfl_xor(s3, 1);

    if (r == 0 && (size_t)3 * NVISD + gv < (size_t)out_elems) {
        out[0 * NVISD + gv] = s0 * FH_ISCALE;
        out[1 * NVISD + gv] = s1 * FH_ISCALE;
        out[2 * NVISD + gv] = s2 * FH_ISCALE;
        out[3 * NVISD + gv] = s3 * FH_ISCALE;
    }
}

// ---------------- gather6 (full, complexOut fallback) ----------------
__global__ __launch_bounds__(256) void gather6(const float* __restrict__ uu,
                                               const float* __restrict__ vv,
                                               const float4* __restrict__ FhH4,
                                               const float* __restrict__ FhIm,
                                               const float* __restrict__ Wtab,
                                               float* __restrict__ out,
                                               int out_elems) {
    int tid = (int)threadIdx.x;
    int v = tid >> 1, r = tid & 1;
    int gv = blockIdx.x * 128 + v;
    if (gv >= NVISD) return;
    float tx = uu[gv] * SCALE_F;
    float ty = vv[gv] * SCALE_F;
    float fxf = floorf(tx), fyf = floorf(ty);
    int fxi = (int)fxf, fyi = (int)fyf;

    float wxf[6], wy[6];
    wtab_lookup(Wtab, tx - fxf, wxf);
    wtab_lookup(Wtab, ty - fyf, wy);

    float wx[3]; int kxr[3]; int cjr[3];
    #pragma unroll
    for (int bb = 0; bb < 3; ++bb) {
        int b = r * 3 + bb, o = b - 2;
        wx[bb] = wxf[b];
        int ix = (fxi + o) & (GD - 1);
        int cj = (ix > 1024) ? 1 : 0;
        int kx = cj ? (GD - ix) : ix;
        kxr[bb] = min(kx, KXROWS - 1);
        cjr[bb] = cj;
    }

    int p0n = fyi + 414, p0c = 413 - fyi;
    p0n = min(max(p0n, 0), YPACK - 6);
    p0c = min(max(p0c, 0), YPACK - 6);
    int dn = p0n & 1, dc = p0c & 1;
    int f0n = (p0n - dn) >> 1, f0c = (p0c - dc) >> 1;
    float wn8[8], wc8[8];
    #pragma unroll
    for (int w = 0; w < 8; ++w) {
        int tn = w - dn; wn8[w] = (tn >= 0 && tn < 6) ? wy[tn] : 0.0f;
        int tc = w - dc; wc8[w] = (tc >= 0 && tc < 6) ? wy[5 - tc] : 0.0f;
    }

    float s0 = 0.0f, s1 = 0.0f, s2 = 0.0f, s3 = 0.0f;
    #pragma unroll
    for (int bb = 0; bb < 3; ++bb) {
        const float4* rp = FhH4 + (size_t)kxr[bb] * (YPACK / 2);
        bool cj = cjr[bb] != 0;
        int f0 = cj ? f0c : f0n;
        float wxb = wx[bb];
        #pragma unroll
        for (int q = 0; q < 4; ++q) {
            float4 Qv = rp[f0 + q];
            float w0 = wxb * (cj ? wc8[2 * q]     : wn8[2 * q]);
            float w1 = wxb * (cj ? wc8[2 * q + 1] : wn8[2 * q + 1]);
            float2 fa = __half22float2(*reinterpret_cast<const __half2*>(&Qv.x));
            float2 fb = __half22float2(*reinterpret_cast<const __half2*>(&Qv.y));
            float2 fc = __half22float2(*reinterpret_cast<const __half2*>(&Qv.z));
            float2 fd = __half22float2(*reinterpret_cast<const __half2*>(&Qv.w));
            s0 = fmaf(w0, fa.x, fmaf(w1, fc.x, s0));
            s1 = fmaf(w0, fa.y, fmaf(w1, fc.y, s1));
            s2 = fmaf(w0, fb.x, fmaf(w1, fd.x, s2));
            s3 = fmaf(w0, fb.y, fmaf(w1, fd.y, s3));
        }
    }
    s0 += __shfl_xor(s0, 1);
    s1 += __shfl_xor(s1, 1);
    s2 += __shfl_xor(s2, 1);
    s3 += __shfl_xor(s3, 1);

    float sr[4] = {s0, s1, s2, s3};
    #pragma unroll
    for (int c = 0; c < NCHAND; ++c) {
        float sy = 0.0f;
        const float* baseI = FhIm + (size_t)c * KXROWS * YPACK;
        #pragma unroll
        for (int bb = 0; bb < 3; ++bb) {
            const float* rp = baseI + (size_t)kxr[bb] * YPACK;
            bool cj = cjr[bb] != 0;
            float wxb = wx[bb];
            #pragma unroll
            for (int a = 0; a < 6; ++a) {
                int yv = fyi + (a - 2);
                int pos = cj ? (416 - yv) : (yv + 416);
                pos = min(max(pos, 0), YPACK - 1);
                float w = wxb * wy[a];
                sy = fmaf(cj ? -w : w, rp[pos], sy);
            }
        }
        sy += __shfl_xor(sy, 1);
        size_t oidx = (size_t)c * NVISD + gv;
        if (r == 0 && 2 * oidx + 1 < (size_t)out_elems) {
            out[2 * oidx] = sr[c] * FH_ISCALE;
            out[2 * oidx + 1] = sy;
        }
    }
}

extern "C" void kernel_launch(void* const* d_in, const int* in_sizes, int n_in,
                              void* d_out, int out_size, void* d_ws, size_t ws_size,
                              hipStream_t stream) {
    (void)in_sizes; (void)n_in;
    const float* img = (const float*)d_in[0];
    const float* uu  = (const float*)d_in[1];
    const float* vv  = (const float*)d_in[2];

    const size_t finBytes  = (size_t)NCHAND * KXROWS * FINP * sizeof(unsigned int); // 6.68 MB
    const size_t fhhBytes  = (size_t)KXROWS * YPACK * NCHAND * sizeof(__half);      // 2.72 MB
    const size_t fhimBytes = (size_t)NCHAND * KXROWS * YPACK * sizeof(float);       // 5.43 MB
    const size_t wtabBytes = 1025 * 8 * sizeof(float);                              // 32.8 KB
    const size_t need = finBytes + fhhBytes + fhimBytes + wtabBytes;                // ~14.9 MB

    char* ws = (char*)d_ws;
    unsigned int* FinU = (unsigned int*)ws;
    __half* FhH  = (__half*)(ws + finBytes);
    float*  FhIm = (float*)(ws + finBytes + fhhBytes);
    float*  Wtab = (float*)(ws + finBytes + fhhBytes + fhimBytes);

    if (ws_size < need) return;  // diagnostic guard

    int complexOut = (out_size >= 2 * NCHAND * NVISD) ? 1 : 0;

    fft_rows_fused<<<dim3(256, NCHAND), dim3(256), 0, stream>>>(img, FinU);
    fft_cols<<<dim3(KXROWS, NCHAND), dim3(256), 0, stream>>>(FinU, FhH, FhIm, Wtab, complexOut);
    if (complexOut) {
        gather6<<<dim3((NVISD + 127) / 128), dim3(256), 0, stream>>>(
            uu, vv, (const float4*)FhH, FhIm, Wtab, (float*)d_out, out_size);
    } else {
        gather_real<<<dim3((NVISD + 127) / 128), dim3(256), 0, stream>>>(
            uu, vv, (const float4*)FhH, Wtab, (float*)d_out, out_size);
    }
}

// Round 17
// 47.344 us; speedup vs baseline: 1.0559x; 1.0559x over previous
//
#include <hip/hip_runtime.h>
#include <hip/hip_fp16.h>
#include <math.h>

#define NPIXD 1024
#define GD    2048
#define NCHAND 4
#define NVISD 200000
#define KXROWS 408     // kx rows computed/stored (gather needs <=403; clamped)
#define YPACK  832     // centered packing: pos = y_signed + 416
#define FINP   1024    // Fin row pitch (half2 slots)
#define TWN    1792    // twiddle entries: max index 7*255 = 1785 (stage0)
#define IDX(i) ((i) + ((i) >> 4))   // LDS pad
#define RSQ2   0.70710678118654752f

#define FH_SCALE   1048576.0f       // 2^20 net scale of FhH
#define FH_ISCALE  (1.0f / 1048576.0f)
#define FIN_SCALE  4194304.0f       // 2^22 scale of Fin (half2)
#define FIN_TO_FH  0.25f            // 2^22 -> 2^20
#define FIN_TO_IM  (1.0f / 4194304.0f)

static constexpr double PI_D = 3.14159265358979323846;
static constexpr float SCALE_F = (float)(1000.0 * 0.005 * PI_D / (180.0 * 3600.0) * 2048.0);
static constexpr float BETA_F  = (float)(2.34 * 6.0);

// inline apodization: for i in [0,1024), arg >= 173 > 0 always
__device__ __forceinline__ float apodf(int i) {
    float n  = (float)(i - 512) * (1.0f / 2048.0f);
    float t  = (float)(PI_D * 6.0) * n;
    float arg = BETA_F * BETA_F - t * t;
    float sq = sqrtf(arg);
    float e  = __expf(sq);
    return sq * 2.0f / (e - 1.0f / e);     // sq / sinh(sq)
}

__device__ __forceinline__ float2 cadd(float2 a, float2 b){ return make_float2(a.x+b.x, a.y+b.y); }
__device__ __forceinline__ float2 csub(float2 a, float2 b){ return make_float2(a.x-b.x, a.y-b.y); }
__device__ __forceinline__ float2 cmulf(float2 a, float2 b){ return make_float2(a.x*b.x - a.y*b.y, a.x*b.y + a.y*b.x); }
__device__ __forceinline__ float2 cnegi(float2 a){ return make_float2(a.y, -a.x); }

// fill LDS twiddle table: twl[t] = exp(-i*pi*t/1024), t in [0,1792)
__device__ __forceinline__ void fill_twl(float2* __restrict__ twl) {
    for (int t = (int)threadIdx.x; t < TWN; t += 256) {
        float s, c;
        __sincosf((float)t * (float)(-PI_D / 1024.0), &s, &c);
        twl[t] = make_float2(c, s);
    }
}

// DFT8 with x2..x5 == 0
__device__ __forceinline__ void dft8_sparse(float2 x0, float2 x1, float2 x6, float2 x7,
                                            float2 y[8]) {
    float2 u0 = cadd(x0,x6), u1 = csub(x0,x6), u2 = cadd(x1,x7), u3 = cnegi(csub(x1,x7));
    y[0]=cadd(u0,u2); y[2]=cadd(u1,u3); y[4]=csub(u0,u2); y[6]=csub(u1,u3);
    float2 o0 = x0;
    float2 o1 = make_float2(RSQ2*(x1.x + x1.y), RSQ2*(x1.y - x1.x));
    float2 o2 = make_float2(-x6.y, x6.x);
    float2 o3 = make_float2(RSQ2*(x7.x - x7.y), RSQ2*(x7.y + x7.x));
    float2 v0 = cadd(o0,o2), v1 = csub(o0,o2), v2 = cadd(o1,o3), v3 = cnegi(csub(o1,o3));
    y[1]=cadd(v0,v2); y[3]=cadd(v1,v3); y[5]=csub(v0,v2); y[7]=csub(v1,v3);
}

__device__ __forceinline__ void dft8_full(const float2 x[8], float2 y[8]) {
    float2 e0=cadd(x[0],x[4]), e1=cadd(x[1],x[5]), e2=cadd(x[2],x[6]), e3=cadd(x[3],x[7]);
    float2 o0=csub(x[0],x[4]), o1=csub(x[1],x[5]), o2=csub(x[2],x[6]), o3=csub(x[3],x[7]);
    o1 = make_float2(RSQ2*(o1.x + o1.y), RSQ2*(o1.y - o1.x));
    o2 = cnegi(o2);
    o3 = make_float2(RSQ2*(o3.y - o3.x), -RSQ2*(o3.x + o3.y));
    float2 u0=cadd(e0,e2), u1=csub(e0,e2), u2=cadd(e1,e3), u3=cnegi(csub(e1,e3));
    y[0]=cadd(u0,u2); y[2]=cadd(u1,u3); y[4]=csub(u0,u2); y[6]=csub(u1,u3);
    float2 v0=cadd(o0,o2), v1=csub(o0,o2), v2=cadd(o1,o3), v3=cnegi(csub(o1,o3));
    y[1]=cadd(v0,v2); y[3]=cadd(v1,v3); y[5]=csub(v0,v2); y[7]=csub(v1,v3);
}

// stage 0 (m=1, pm=j): sparse DFT8 from registers -> buf; twiddles from LDS table
__device__ __forceinline__ void stage0_ip(float2 x0, float2 x1, float2 x6, float2 x7,
                                          float2* __restrict__ buf,
                                          const float2* __restrict__ twl) {
    int j = (int)threadIdx.x;
    float2 y[8];
    dft8_sparse(x0, x1, x6, x7, y);
    buf[IDX(8 * j)] = y[0];
    #pragma unroll
    for (int t = 1; t < 8; ++t)
        buf[IDX(8 * j + t)] = cmulf(twl[t * j], y[t]);
}

// in-place radix-8 Stockham stage: read-all, barrier, write-all. m in {8, 64}
__device__ __forceinline__ void r8_ip(float2* __restrict__ buf, int m,
                                      const float2* __restrict__ twl) {
    int j = (int)threadIdx.x;
    float2 x[8];
    #pragma unroll
    for (int k = 0; k < 8; ++k) x[k] = buf[IDX(j + 256 * k)];
    __syncthreads();
    float2 y[8];
    dft8_full(x, y);
    int pm = j & ~(m - 1);
    int base = 7 * pm + j;
    buf[IDX(base)] = y[0];
    #pragma unroll
    for (int t = 1; t < 8; ++t)
        buf[IDX(base + t * m)] = cmulf(twl[t * pm], y[t]);
}

// final radix-4 (m=512, twiddle-free), PRUNED: only t=0 (j) and t=3 (j+1536) written
__device__ __forceinline__ void r4_final_ip(float2* __restrict__ buf) {
    int j = (int)threadIdx.x;
    float2 v[8];
    #pragma unroll
    for (int h = 0; h < 2; ++h) {
        int jj = j + h * 256;
        v[h*4+0] = buf[IDX(jj)];
        v[h*4+1] = buf[IDX(jj + 512)];
        v[h*4+2] = buf[IDX(jj + 1024)];
        v[h*4+3] = buf[IDX(jj + 1536)];
    }
    __syncthreads();
    #pragma unroll
    for (int h = 0; h < 2; ++h) {
        int jj = j + h * 256;
        float2 a = v[h*4], b = v[h*4+1], cc = v[h*4+2], d = v[h*4+3];
        float2 u0 = cadd(a,cc), u1 = csub(a,cc), u2 = cadd(b,d), u3 = cnegi(csub(b,d));
        buf[IDX(jj)]        = cadd(u0,u2);   // t=0
        buf[IDX(jj + 1536)] = csub(u1,u3);   // t=3
    }
}

// ---------------- Kaiser-Bessel weights (used only for table fill) ----------------
__device__ __forceinline__ float i0f(float x) {
    float ax = fabsf(x);
    if (ax <= 3.75f) {
        float ts = ax / 3.75f; ts *= ts;
        return 1.0f + ts * (3.5156229f + ts * (3.0899424f + ts * (1.2067492f +
                     ts * (0.2659732f + ts * (0.0360768f + ts * 0.0045813f)))));
    } else {
        float t = 3.75f / ax;
        return expf(ax) / sqrtf(ax) *
               (0.39894228f + t * (0.01328592f + t * (0.00225319f + t * (-0.00157565f +
                t * (0.00916281f + t * (-0.02057706f + t * (0.02635537f +
                t * (-0.01647633f + t * 0.00392377f))))))));
    }
}

__device__ __forceinline__ float kbwf(float dist) {
    float r = dist * (2.0f / 6.0f);
    float s = 1.0f - r * r;
    if (s <= 0.0f) return 0.0f;
    return i0f(BETA_F * sqrtf(s)) * (1.0f / 6.0f);
}

// ---------------- pass 1 FUSED: 2 CONSECUTIVE row-pairs/block (y0..y0+3), half2 Fin ----
__global__ __launch_bounds__(256) void fft_rows_fused(const float* __restrict__ img,
                                                      unsigned int* __restrict__ FinU) {
    __shared__ float2 buf[2176];
    __shared__ float2 twl[TWN];
    __shared__ unsigned int stg[KXROWS * 5];   // 4 half2 per kx + pad (pitch 5)
    int j  = (int)threadIdx.x;
    int bx = (int)blockIdx.x;                  // 0..255
    int c  = (int)blockIdx.y;
    int w  = (bx & 7) * 32 + (bx >> 3);        // bijective on [0,256); same-XCD w consecutive
    int y0 = w * 4;
    fill_twl(twl);
    float a0 = apodf(j + 512), a1 = apodf(j + 768), a6 = apodf(j), a7 = apodf(j + 256);
    float ay[4];
    #pragma unroll
    for (int p = 0; p < 4; ++p) ay[p] = apodf(y0 + p);
    float rA[4][4];
    #pragma unroll
    for (int p = 0; p < 4; ++p) {
        const float* rp = img + ((size_t)c * NPIXD + y0 + p) * NPIXD;
        rA[p][0] = rp[j + 512]; rA[p][1] = rp[j + 768];
        rA[p][2] = rp[j];       rA[p][3] = rp[j + 256];
    }
    #pragma unroll
    for (int q = 0; q < 2; ++q) {
        int pa = 2 * q, pb = 2 * q + 1;
        float ay1 = ay[pa], ay2 = ay[pb];
        float2 x0 = make_float2(rA[pa][0] * a0 * ay1, rA[pb][0] * a0 * ay2);
        float2 x1 = make_float2(rA[pa][1] * a1 * ay1, rA[pb][1] * a1 * ay2);
        float2 x6 = make_float2(rA[pa][2] * a6 * ay1, rA[pb][2] * a6 * ay2);
        float2 x7 = make_float2(rA[pa][3] * a7 * ay1, rA[pb][3] * a7 * ay2);
        __syncthreads();                     // buf free (prev epilogue) + twl fill visible
        stage0_ip(x0, x1, x6, x7, buf, twl);
        __syncthreads();
        r8_ip(buf, 8, twl);
        __syncthreads();
        r8_ip(buf, 64, twl);
        __syncthreads();
        r4_final_ip(buf);
        __syncthreads();
        // Hermitian unpair epilogue -> stage (half2 bits, scaled 2^22)
        #pragma unroll
        for (int t = 0; t < 2; ++t) {
            int kx = j + t * 256;
            if (kx < KXROWS) {
                float2 Z  = buf[IDX(kx)];
                float2 Zm = buf[IDX((GD - kx) & (GD - 1))];
                __half2 h1 = __floats2half2_rn(0.5f*(Z.x+Zm.x)*FIN_SCALE, 0.5f*(Z.y-Zm.y)*FIN_SCALE);
                __half2 h2v = __floats2half2_rn(0.5f*(Z.y+Zm.y)*FIN_SCALE, 0.5f*(Zm.x-Z.x)*FIN_SCALE);
                stg[kx * 5 + pa] = *reinterpret_cast<unsigned int*>(&h1);
                stg[kx * 5 + pb] = *reinterpret_cast<unsigned int*>(&h2v);
            }
        }
    }
    __syncthreads();
    // write-out: one 16B chunk (4 half2 = rows y0..y0+3) per kx
    #pragma unroll
    for (int k = 0; k < 2; ++k) {
        int kx = j + 256 * k;
        if (kx < KXROWS) {
            unsigned int* dst = FinU + ((size_t)c * KXROWS + kx) * FINP + y0;
            const unsigned int* s = &stg[kx * 5];
            *reinterpret_cast<uint4*>(dst) = make_uint4(s[0], s[1], s[2], s[3]);
        }
    }
}

// ---------------- pass 2: col FFTs from half2 Fin; Re -> half4 interleaved --------------
// Block (0,0) additionally fills the 1025x8 KB-weight lerp table for the gather.
__global__ __launch_bounds__(256) void fft_cols(const unsigned int* __restrict__ FinU,
                                                __half* __restrict__ FhH,
                                                float* __restrict__ FhIm,
                                                float* __restrict__ Wtab,
                                                int writeIm) {
    __shared__ float2 buf[2176];
    __shared__ float2 twl[TWN];
    int j = (int)threadIdx.x;
    int kx = blockIdx.x, c = blockIdx.y;
    fill_twl(twl);
    if (kx == 0 && c == 0) {
        for (int i = j; i <= 1024; i += 256) {
            float frac = (float)i * (1.0f / 1024.0f);
            float* rowp = Wtab + (size_t)i * 8;
            #pragma unroll
            for (int o = 0; o < 6; ++o) rowp[o] = kbwf(frac - (float)(o - 2));
            rowp[6] = 0.0f; rowp[7] = 0.0f;
        }
    }
    const unsigned int* inr = FinU + ((size_t)c * KXROWS + kx) * FINP;
    unsigned int u0 = inr[j + 512], u1 = inr[j + 768], u6 = inr[j], u7 = inr[j + 256];
    float2 x0 = __half22float2(*reinterpret_cast<__half2*>(&u0));
    float2 x1 = __half22float2(*reinterpret_cast<__half2*>(&u1));
    float2 x6 = __half22float2(*reinterpret_cast<__half2*>(&u6));
    float2 x7 = __half22float2(*reinterpret_cast<__half2*>(&u7));
    __syncthreads();                         // twl fill visible
    stage0_ip(x0, x1, x6, x7, buf, twl);
    __syncthreads();
    r8_ip(buf, 8, twl);
    __syncthreads();
    r8_ip(buf, 64, twl);
    __syncthreads();
    r4_final_ip(buf);
    __syncthreads();
    // centered packing: n<416 -> pos n+416 (y=n); n>=1632 -> pos n-1632 (y=n-2048)
    __half* basep = FhH + ((size_t)kx * YPACK) * NCHAND + c;
    float*  imb   = FhIm + ((size_t)c * KXROWS + kx) * YPACK;
    for (int n = j; n < GD; n += 256) {
        int pos = -1;
        if (n < 416)         pos = n + 416;
        else if (n >= 1632)  pos = n - 1632;
        if (pos >= 0) {
            float2 z = buf[IDX(n)];
            basep[(size_t)pos * NCHAND] = __float2half_rn(z.x * FIN_TO_FH);
            if (writeIm) imb[pos] = z.y * FIN_TO_IM;
        }
    }
}

// ---- 6-weight lookup with linear interpolation: w6[o] = w(frac - (o-2)) ----
__device__ __forceinline__ void wtab_lookup(const float* __restrict__ Wtab, float frac,
                                            float w6[6]) {
    float fu = frac * 1024.0f;
    int   iu = (int)fu;                 // 0..1023
    float aa = fu - (float)iu;
    const float4* rw = (const float4*)(Wtab + (size_t)iu * 8);
    float4 A0 = rw[0], A1 = rw[1], B0 = rw[2], B1 = rw[3];
    w6[0] = fmaf(aa, B0.x - A0.x, A0.x);
    w6[1] = fmaf(aa, B0.y - A0.y, A0.y);
    w6[2] = fmaf(aa, B0.z - A0.z, A0.z);
    w6[3] = fmaf(aa, B0.w - A0.w, A0.w);
    w6[4] = fmaf(aa, B1.x - A1.x, A1.x);
    w6[5] = fmaf(aa, B1.y - A1.y, A1.y);
}

// ---------------- gather_real: dead complex path stripped; loads issued first ----------
__global__ __launch_bounds__(256) void gather_real(const float* __restrict__ uu,
                                                   const float* __restrict__ vv,
                                                   const float4* __restrict__ FhH4,
                                                   const float* __restrict__ Wtab,
                                                   float* __restrict__ out,
                                                   int out_elems) {
    int tid = (int)threadIdx.x;
    int v = tid >> 1, r = tid & 1;
    int gv = blockIdx.x * 128 + v;
    if (gv >= NVISD) return;
    float tx = uu[gv] * SCALE_F;
    float ty = vv[gv] * SCALE_F;
    float fxf = floorf(tx), fyf = floorf(ty);
    int fxi = (int)fxf, fyi = (int)fyf;

    int p0n = fyi + 414, p0c = 413 - fyi;
    p0n = min(max(p0n, 0), YPACK - 6);
    p0c = min(max(p0c, 0), YPACK - 6);
    int dn = p0n & 1, dc = p0c & 1;
    int f0n = (p0n - dn) >> 1, f0c = (p0c - dc) >> 1;

    const float4* rps[3];
    int cjs[3];
    #pragma unroll
    for (int bb = 0; bb < 3; ++bb) {
        int o = r * 3 + bb - 2;
        int ix = (fxi + o) & (GD - 1);
        int cj = (ix > 1024) ? 1 : 0;
        int kx = cj ? (GD - ix) : ix;
        kx = min(kx, KXROWS - 1);
        rps[bb] = FhH4 + (size_t)kx * (YPACK / 2) + (cj ? f0c : f0n);
        cjs[bb] = cj;
    }

    float4 Q[3][4];
    #pragma unroll
    for (int bb = 0; bb < 3; ++bb) {
        #pragma unroll
        for (int q = 0; q < 4; ++q) Q[bb][q] = rps[bb][q];
    }

    float wxf[6], wy[6];
    wtab_lookup(Wtab, tx - fxf, wxf);
    wtab_lookup(Wtab, ty - fyf, wy);
    float wn8[8], wc8[8];
    #pragma unroll
    for (int w = 0; w < 8; ++w) {
        int tn = w - dn; wn8[w] = (tn >= 0 && tn < 6) ? wy[tn] : 0.0f;
        int tc = w - dc; wc8[w] = (tc >= 0 && tc < 6) ? wy[5 - tc] : 0.0f;
    }

    float s0 = 0.0f, s1 = 0.0f, s2 = 0.0f, s3 = 0.0f;
    #pragma unroll
    for (int bb = 0; bb < 3; ++bb) {
        float wxb = wxf[r * 3 + bb];
        bool cj = cjs[bb] != 0;
        #pragma unroll
        for (int q = 0; q < 4; ++q) {
            float4 Qv = Q[bb][q];
            float w0 = wxb * (cj ? wc8[2 * q]     : wn8[2 * q]);
            float w1 = wxb * (cj ? wc8[2 * q + 1] : wn8[2 * q + 1]);
            float2 fa = __half22float2(*reinterpret_cast<const __half2*>(&Qv.x));
            float2 fb = __half22float2(*reinterpret_cast<const __half2*>(&Qv.y));
            float2 fc = __half22float2(*reinterpret_cast<const __half2*>(&Qv.z));
            float2 fd = __half22float2(*reinterpret_cast<const __half2*>(&Qv.w));
            s0 = fmaf(w0, fa.x, fmaf(w1, fc.x, s0));
            s1 = fmaf(w0, fa.y, fmaf(w1, fc.y, s1));
            s2 = fmaf(w0, fb.x, fmaf(w1, fd.x, s2));
            s3 = fmaf(w0, fb.y, fmaf(w1, fd.y, s3));
        }
    }
    s0 += __shfl_xor(s0, 1);
    s1 += __shfl_xor(s1, 1);
    s2 += __shfl_xor(s2, 1);
    s3 += __shfl_xor(s3, 1);

    if (r == 0 && (size_t)3 * NVISD + gv < (size_t)out_elems) {
        out[0 * NVISD + gv] = s0 * FH_ISCALE;
        out[1 * NVISD + gv] = s1 * FH_ISCALE;
        out[2 * NVISD + gv] = s2 * FH_ISCALE;
        out[3 * NVISD + gv] = s3 * FH_ISCALE;
    }
}

// ---------------- gather6 (full, complexOut fallback) ----------------
__global__ __launch_bounds__(256) void gather6(const float* __restrict__ uu,
                                               const float* __restrict__ vv,
                                               const float4* __restrict__ FhH4,
                                               const float* __restrict__ FhIm,
                                               const float* __restrict__ Wtab,
                                               float* __restrict__ out,
                                               int out_elems) {
    int tid = (int)threadIdx.x;
    int v = tid >> 1, r = tid & 1;
    int gv = blockIdx.x * 128 + v;
    if (gv >= NVISD) return;
    float tx = uu[gv] * SCALE_F;
    float ty = vv[gv] * SCALE_F;
    float fxf = floorf(tx), fyf = floorf(ty);
    int fxi = (int)fxf, fyi = (int)fyf;

    float wxf[6], wy[6];
    wtab_lookup(Wtab, tx - fxf, wxf);
    wtab_lookup(Wtab, ty - fyf, wy);

    float wx[3]; int kxr[3]; int cjr[3];
    #pragma unroll
    for (int bb = 0; bb < 3; ++bb) {
        int b = r * 3 + bb, o = b - 2;
        wx[bb] = wxf[b];
        int ix = (fxi + o) & (GD - 1);
        int cj = (ix > 1024) ? 1 : 0;
        int kx = cj ? (GD - ix) : ix;
        kxr[bb] = min(kx, KXROWS - 1);
        cjr[bb] = cj;
    }

    int p0n = fyi + 414, p0c = 413 - fyi;
    p0n = min(max(p0n, 0), YPACK - 6);
    p0c = min(max(p0c, 0), YPACK - 6);
    int dn = p0n & 1, dc = p0c & 1;
    int f0n = (p0n - dn) >> 1, f0c = (p0c - dc) >> 1;
    float wn8[8], wc8[8];
    #pragma unroll
    for (int w = 0; w < 8; ++w) {
        int tn = w - dn; wn8[w] = (tn >= 0 && tn < 6) ? wy[tn] : 0.0f;
        int tc = w - dc; wc8[w] = (tc >= 0 && tc < 6) ? wy[5 - tc] : 0.0f;
    }

    float s0 = 0.0f, s1 = 0.0f, s2 = 0.0f, s3 = 0.0f;
    #pragma unroll
    for (int bb = 0; bb < 3; ++bb) {
        const float4* rp = FhH4 + (size_t)kxr[bb] * (YPACK / 2);
        bool cj = cjr[bb] != 0;
        int f0 = cj ? f0c : f0n;
        float wxb = wx[bb];
        #pragma unroll
        for (int q = 0; q < 4; ++q) {
            float4 Qv = rp[f0 + q];
            float w0 = wxb * (cj ? wc8[2 * q]     : wn8[2 * q]);
            float w1 = wxb * (cj ? wc8[2 * q + 1] : wn8[2 * q + 1]);
            float2 fa = __half22float2(*reinterpret_cast<const __half2*>(&Qv.x));
            float2 fb = __half22float2(*reinterpret_cast<const __half2*>(&Qv.y));
            float2 fc = __half22float2(*reinterpret_cast<const __half2*>(&Qv.z));
            float2 fd = __half22float2(*reinterpret_cast<const __half2*>(&Qv.w));
            s0 = fmaf(w0, fa.x, fmaf(w1, fc.x, s0));
            s1 = fmaf(w0, fa.y, fmaf(w1, fc.y, s1));
            s2 = fmaf(w0, fb.x, fmaf(w1, fd.x, s2));
            s3 = fmaf(w0, fb.y, fmaf(w1, fd.y, s3));
        }
    }
    s0 += __shfl_xor(s0, 1);
    s1 += __shfl_xor(s1, 1);
    s2 += __shfl_xor(s2, 1);
    s3 += __shfl_xor(s3, 1);

    float sr[4] = {s0, s1, s2, s3};
    #pragma unroll
    for (int c = 0; c < NCHAND; ++c) {
        float sy = 0.0f;
        const float* baseI = FhIm + (size_t)c * KXROWS * YPACK;
        #pragma unroll
        for (int bb = 0; bb < 3; ++bb) {
            const float* rp = baseI + (size_t)kxr[bb] * YPACK;
            bool cj = cjr[bb] != 0;
            float wxb = wx[bb];
            #pragma unroll
            for (int a = 0; a < 6; ++a) {
                int yv = fyi + (a - 2);
                int pos = cj ? (416 - yv) : (yv + 416);
                pos = min(max(pos, 0), YPACK - 1);
                float w = wxb * wy[a];
                sy = fmaf(cj ? -w : w, rp[pos], sy);
            }
        }
        sy += __shfl_xor(sy, 1);
        size_t oidx = (size_t)c * NVISD + gv;
        if (r == 0 && 2 * oidx + 1 < (size_t)out_elems) {
            out[2 * oidx] = sr[c] * FH_ISCALE;
            out[2 * oidx + 1] = sy;
        }
    }
}

extern "C" void kernel_launch(void* const* d_in, const int* in_sizes, int n_in,
                              void* d_out, int out_size, void* d_ws, size_t ws_size,
                              hipStream_t stream) {
    (void)in_sizes; (void)n_in;
    const float* img = (const float*)d_in[0];
    const float* uu  = (const float*)d_in[1];
    const float* vv  = (const float*)d_in[2];

    const size_t finBytes  = (size_t)NCHAND * KXROWS * FINP * sizeof(unsigned int); // 6.68 MB
    const size_t fhhBytes  = (size_t)KXROWS * YPACK * NCHAND * sizeof(__half);      // 2.72 MB
    const size_t fhimBytes = (size_t)NCHAND * KXROWS * YPACK * sizeof(float);       // 5.43 MB
    const size_t wtabBytes = 1025 * 8 * sizeof(float);                              // 32.8 KB
    const size_t need = finBytes + fhhBytes + fhimBytes + wtabBytes;                // ~14.9 MB

    char* ws = (char*)d_ws;
    unsigned int* FinU = (unsigned int*)ws;
    __half* FhH  = (__half*)(ws + finBytes);
    float*  FhIm = (float*)(ws + finBytes + fhhBytes);
    float*  Wtab = (float*)(ws + finBytes + fhhBytes + fhimBytes);

    if (ws_size < need) return;  // diagnostic guard

    int complexOut = (out_size >= 2 * NCHAND * NVISD) ? 1 : 0;

    fft_rows_fused<<<dim3(256, NCHAND), dim3(256), 0, stream>>>(img, FinU);
    fft_cols<<<dim3(KXROWS, NCHAND), dim3(256), 0, stream>>>(FinU, FhH, FhIm, Wtab, complexOut);
    if (complexOut) {
        gather6<<<dim3((NVISD + 127) / 128), dim3(256), 0, stream>>>(
            uu, vv, (const float4*)FhH, FhIm, Wtab, (float*)d_out, out_size);
    } else {
        gather_real<<<dim3((NVISD + 127) / 128), dim3(256), 0, stream>>>(
            uu, vv, (const float4*)FhH, Wtab, (float*)d_out, out_size);
    }
}